// Round 4
// baseline (160.313 us; speedup 1.0000x reference)
//
#include <hip/hip_runtime.h>
#include <hip/hip_cooperative_groups.h>
#include <math.h>

namespace cg = cooperative_groups;

#define MARGIN 1.9f
#define TILE 32
#define NMAX 1024   // max n supported by the LDS row layout (n=640 here)

// ===========================================================================
// Fused single-dispatch kernel (cooperative launch).
//   Phase 1 (blocks 0..nt*nt-1): 32x32 dist tile via LDS-tiled GEMM on
//     sum((a-b)^2). Byte-for-byte the round-0/3 dist kernel numerics.
//   grid.sync()
//   Phase 2 (blocks 0..n-1): per-anchor triplet sweep, byte-for-byte the
//     round-0/3 triplet body, + ticketed last-block finalize (round-3 proven).
// LDS arena is shared between phases (no data persists across grid.sync).
// ===========================================================================
__global__ __launch_bounds__(256) void fused_all(
        const float* __restrict__ e, const int* __restrict__ lab,
        int n, int d,
        float* __restrict__ dist,
        float* __restrict__ part_sum,          // [n]
        unsigned int* __restrict__ part_ne,    // [n]
        unsigned int* __restrict__ part_valid, // [n]
        unsigned int* __restrict__ done_counter,
        float* __restrict__ out)               // [4]
{
    __shared__ __align__(16) float arena[2 * TILE * 132];  // 33792 B
    __shared__ int p_cnt, n_cnt;
    __shared__ float red_s[4];
    __shared__ unsigned int red_c[4];
    __shared__ unsigned int ticket_s;

    const int tid  = threadIdx.x;
    const int lane = tid & 63;
    const int wv   = tid >> 6;
    const int b    = blockIdx.x;
    const int nf4  = d >> 2;                    // float4s per row (32)
    const int nt   = (n + TILE - 1) / TILE;     // 20
    const float4* eg = (const float4*)e;

    if (b == 0 && tid == 0) *done_counter = 0u; // published by grid.sync fence

    // ---------------- phase 1: dist tiles --------------------------------
    if (b < nt * nt) {
        float4* As4 = (float4*)arena;
        float4* Bs4 = (float4*)(arena + TILE * 132);
        const int row0 = (b / nt) * TILE;
        const int col0 = (b % nt) * TILE;
        for (int f = tid; f < TILE * nf4; f += 256) {
            int r = f / nf4, c = f - r * nf4;
            int ga = row0 + r; if (ga >= n) ga = n - 1;   // clamp (n%32==0 here)
            int gb = col0 + r; if (gb >= n) gb = n - 1;
            As4[r * 33 + c] = eg[(size_t)ga * nf4 + c];
            Bs4[r * 33 + c] = eg[(size_t)gb * nf4 + c];
        }
        __syncthreads();

        const int tx = tid & 15, ty = tid >> 4;
        float a00 = 0.f, a01 = 0.f, a10 = 0.f, a11 = 0.f;
        for (int t = 0; t < nf4; ++t) {
            float4 A0 = As4[ty * 33 + t];
            float4 A1 = As4[(ty + 16) * 33 + t];
            float4 B0 = Bs4[tx * 33 + t];
            float4 B1 = Bs4[tx * 33 + 16 * 33 + t];
            float dx;
#define ACC(acc, A, B, comp) dx = A.comp - B.comp; acc = fmaf(dx, dx, acc)
            ACC(a00, A0, B0, x); ACC(a00, A0, B0, y); ACC(a00, A0, B0, z); ACC(a00, A0, B0, w);
            ACC(a01, A0, B1, x); ACC(a01, A0, B1, y); ACC(a01, A0, B1, z); ACC(a01, A0, B1, w);
            ACC(a10, A1, B0, x); ACC(a10, A1, B0, y); ACC(a10, A1, B0, z); ACC(a10, A1, B0, w);
            ACC(a11, A1, B1, x); ACC(a11, A1, B1, y); ACC(a11, A1, B1, z); ACC(a11, A1, B1, w);
#undef ACC
        }

        const int r0 = row0 + ty, r1 = row0 + ty + 16;
        const int c0 = col0 + tx, c1 = col0 + tx + 16;
#define EMIT(rr, cc, acc) if ((rr) < n && (cc) < n) \
        dist[(size_t)(rr) * n + (cc)] = ((acc) == 0.f) ? 0.f : sqrtf(acc)
        EMIT(r0, c0, a00); EMIT(r0, c1, a01);
        EMIT(r1, c0, a10); EMIT(r1, c1, a11);
#undef EMIT
    }

    cg::this_grid().sync();   // dist visible device-wide; arena reusable

    // ---------------- phase 2: per-anchor triplet sweep -------------------
    const int i = b;
    if (i < n) {
        float* row  = arena;                     // n floats
        float* pos  = arena + NMAX;              // n floats
        int*   labs = (int*)(arena + 2 * NMAX);  // n ints (12 KB total <= arena)

        if (tid == 0) { p_cnt = 0; n_cnt = 0; }
        for (int j = tid; j < n; j += 256) {
            row[j]  = dist[(size_t)i * n + j];
            labs[j] = lab[j];
        }
        __syncthreads();

        const int my_lab = labs[i];
        int local_neg = 0;
        for (int j = tid; j < n; j += 256) {
            if (labs[j] == my_lab) {
                if (j != i) { int k = atomicAdd(&p_cnt, 1); pos[k] = row[j]; }
            } else {
                local_neg++;
            }
        }
        for (int off = 32; off > 0; off >>= 1) local_neg += __shfl_down(local_neg, off, 64);
        if (lane == 0) atomicAdd(&n_cnt, local_neg);

        // negatives as INF-padded registers (NMAX/256 = 4 slots)
        const float INF = __builtin_huge_valf();
        int j0 = tid, j1 = tid + 256, j2 = tid + 512, j3 = tid + 768;
        float n0 = (j0 < n && labs[j0] != my_lab) ? row[j0] : INF;
        float n1 = (j1 < n && labs[j1] != my_lab) ? row[j1] : INF;
        float n2 = (j2 < n && labs[j2] != my_lab) ? row[j2] : INF;
        float n3 = (j3 < n && labs[j3] != my_lab) ? row[j3] : INF;
        __syncthreads();
        const int P = p_cnt, N = n_cnt;

        float sum = 0.f;
        unsigned int c = 0;
        for (int j = 0; j < P; ++j) {
            float a = pos[j] + MARGIN;        // LDS broadcast
            float t0 = a - n0; if (t0 > 0.f) { sum += t0; c++; }
            float t1 = a - n1; if (t1 > 0.f) { sum += t1; c++; }
            float t2 = a - n2; if (t2 > 0.f) { sum += t2; c++; }
            float t3 = a - n3; if (t3 > 0.f) { sum += t3; c++; }
        }

        for (int off = 32; off > 0; off >>= 1) {
            sum += __shfl_down(sum, off, 64);
            c   += __shfl_down(c,   off, 64);
        }
        if (lane == 0) { red_s[wv] = sum; red_c[wv] = c; }
        __syncthreads();

        if (tid == 0) {
            float s = 0.f; unsigned int cc = 0;
            for (int w = 0; w < 4; ++w) { s += red_s[w]; cc += red_c[w]; }
            part_sum[i]   = s;
            part_ne[i]    = cc;
            part_valid[i] = (unsigned int)P * (unsigned int)N;
            __threadfence();                                   // release partials
            ticket_s = atomicAdd(done_counter, 1u);            // device-scope
        }
        __syncthreads();

        if (ticket_s == (unsigned int)n - 1u) {
            // ---- last block: finalize (identical order to prior finalize) ----
            __threadfence();                                   // acquire partials
            volatile const float*        vs = (volatile const float*)part_sum;
            volatile const unsigned int* vn = (volatile const unsigned int*)part_ne;
            volatile const unsigned int* vv = (volatile const unsigned int*)part_valid;

            float s = 0.f;
            unsigned long long ne = 0, nv = 0;
            for (int q = tid; q < n; q += 256) {
                s  += vs[q];
                ne += vn[q];
                nv += vv[q];
            }
            for (int off = 32; off > 0; off >>= 1) {
                s  += __shfl_down(s,  off, 64);
                ne += __shfl_down(ne, off, 64);
                nv += __shfl_down(nv, off, 64);
            }
            __shared__ float fr_s[4];
            __shared__ unsigned long long fr_ne[4], fr_nv[4];
            if (lane == 0) { fr_s[wv] = s; fr_ne[wv] = ne; fr_nv[wv] = nv; }
            __syncthreads();
            if (tid == 0) {
                float ts = 0.f; unsigned long long tne = 0, tnv = 0;
                for (int w = 0; w < 4; ++w) { ts += fr_s[w]; tne += fr_ne[w]; tnv += fr_nv[w]; }
                float fne = (float)tne;
                float fnv = (float)tnv;
                out[0] = (fne > 0.f) ? (ts / fmaxf(fne, 1.f)) : 0.f;
                out[1] = fnv;
                out[2] = fne;
                out[3] = fne / (fnv + 1e-16f);
            }
        }
    }
}

// ===========================================================================
// Fallback path (round-3 proven): two dispatches, used only if the
// cooperative launch is rejected (e.g. by graph capture).
// ===========================================================================
__global__ __launch_bounds__(256) void dist_kernel(
        const float* __restrict__ e, int n, int d,
        float* __restrict__ dist,
        unsigned int* __restrict__ done_counter)
{
    __shared__ float As[TILE * 132];
    __shared__ float Bs[TILE * 132];
    const int tid  = threadIdx.x;
    const int row0 = blockIdx.y * TILE;
    const int col0 = blockIdx.x * TILE;
    const int nf4  = d >> 2;

    if (blockIdx.x == 0 && blockIdx.y == 0 && tid == 0)
        *done_counter = 0u;

    const float4* eg  = (const float4*)e;
    float4* As4 = (float4*)As;
    float4* Bs4 = (float4*)Bs;
    for (int f = tid; f < TILE * nf4; f += 256) {
        int r = f / nf4, c = f - r * nf4;
        int ga = row0 + r; if (ga >= n) ga = n - 1;
        int gb = col0 + r; if (gb >= n) gb = n - 1;
        As4[r * 33 + c] = eg[(size_t)ga * nf4 + c];
        Bs4[r * 33 + c] = eg[(size_t)gb * nf4 + c];
    }
    __syncthreads();

    const int tx = tid & 15, ty = tid >> 4;
    float a00 = 0.f, a01 = 0.f, a10 = 0.f, a11 = 0.f;
    for (int t = 0; t < nf4; ++t) {
        float4 A0 = As4[ty * 33 + t];
        float4 A1 = As4[(ty + 16) * 33 + t];
        float4 B0 = Bs4[tx * 33 + t];
        float4 B1 = Bs4[(tx + 16) * 33 + t];
        float dx;
#define ACC(acc, A, B, comp) dx = A.comp - B.comp; acc = fmaf(dx, dx, acc)
        ACC(a00, A0, B0, x); ACC(a00, A0, B0, y); ACC(a00, A0, B0, z); ACC(a00, A0, B0, w);
        ACC(a01, A0, B1, x); ACC(a01, A0, B1, y); ACC(a01, A0, B1, z); ACC(a01, A0, B1, w);
        ACC(a10, A1, B0, x); ACC(a10, A1, B0, y); ACC(a10, A1, B0, z); ACC(a10, A1, B0, w);
        ACC(a11, A1, B1, x); ACC(a11, A1, B1, y); ACC(a11, A1, B1, z); ACC(a11, A1, B1, w);
#undef ACC
    }

    const int r0 = row0 + ty, r1 = row0 + ty + 16;
    const int c0 = col0 + tx, c1 = col0 + tx + 16;
#define EMIT(rr, cc, acc) if ((rr) < n && (cc) < n) \
        dist[(size_t)(rr) * n + (cc)] = ((acc) == 0.f) ? 0.f : sqrtf(acc)
    EMIT(r0, c0, a00); EMIT(r0, c1, a01);
    EMIT(r1, c0, a10); EMIT(r1, c1, a11);
#undef EMIT
}

__global__ __launch_bounds__(256) void triplet_kernel(
        const float* __restrict__ dist, const int* __restrict__ lab, int n,
        float* __restrict__ part_sum,
        unsigned int* __restrict__ part_ne,
        unsigned int* __restrict__ part_valid,
        unsigned int* __restrict__ done_counter,
        float* __restrict__ out)
{
    __shared__ float row[NMAX];
    __shared__ float pos[NMAX];
    __shared__ int   labs[NMAX];
    __shared__ int p_cnt, n_cnt;
    __shared__ float red_s[4];
    __shared__ unsigned int red_c[4];
    __shared__ unsigned int ticket_s;

    const int i    = blockIdx.x;
    const int tid  = threadIdx.x;
    const int lane = tid & 63;
    const int wv   = tid >> 6;

    if (tid == 0) { p_cnt = 0; n_cnt = 0; }
    for (int j = tid; j < n; j += 256) {
        row[j]  = dist[(size_t)i * n + j];
        labs[j] = lab[j];
    }
    __syncthreads();

    const int my_lab = labs[i];
    int local_neg = 0;
    for (int j = tid; j < n; j += 256) {
        if (labs[j] == my_lab) {
            if (j != i) { int k = atomicAdd(&p_cnt, 1); pos[k] = row[j]; }
        } else {
            local_neg++;
        }
    }
    for (int off = 32; off > 0; off >>= 1) local_neg += __shfl_down(local_neg, off, 64);
    if (lane == 0) atomicAdd(&n_cnt, local_neg);

    const float INF = __builtin_huge_valf();
    int j0 = tid, j1 = tid + 256, j2 = tid + 512, j3 = tid + 768;
    float n0 = (j0 < n && labs[j0] != my_lab) ? row[j0] : INF;
    float n1 = (j1 < n && labs[j1] != my_lab) ? row[j1] : INF;
    float n2 = (j2 < n && labs[j2] != my_lab) ? row[j2] : INF;
    float n3 = (j3 < n && labs[j3] != my_lab) ? row[j3] : INF;
    __syncthreads();
    const int P = p_cnt, N = n_cnt;

    float sum = 0.f;
    unsigned int c = 0;
    for (int j = 0; j < P; ++j) {
        float a = pos[j] + MARGIN;
        float t0 = a - n0; if (t0 > 0.f) { sum += t0; c++; }
        float t1 = a - n1; if (t1 > 0.f) { sum += t1; c++; }
        float t2 = a - n2; if (t2 > 0.f) { sum += t2; c++; }
        float t3 = a - n3; if (t3 > 0.f) { sum += t3; c++; }
    }

    for (int off = 32; off > 0; off >>= 1) {
        sum += __shfl_down(sum, off, 64);
        c   += __shfl_down(c,   off, 64);
    }
    if (lane == 0) { red_s[wv] = sum; red_c[wv] = c; }
    __syncthreads();

    if (tid == 0) {
        float s = 0.f; unsigned int cc = 0;
        for (int w = 0; w < 4; ++w) { s += red_s[w]; cc += red_c[w]; }
        part_sum[i]   = s;
        part_ne[i]    = cc;
        part_valid[i] = (unsigned int)P * (unsigned int)N;
        __threadfence();
        ticket_s = atomicAdd(done_counter, 1u);
    }
    __syncthreads();

    if (ticket_s == (unsigned int)gridDim.x - 1u) {
        __threadfence();
        volatile const float*        vs = (volatile const float*)part_sum;
        volatile const unsigned int* vn = (volatile const unsigned int*)part_ne;
        volatile const unsigned int* vv = (volatile const unsigned int*)part_valid;

        float s = 0.f;
        unsigned long long ne = 0, nv = 0;
        for (int q = tid; q < n; q += 256) {
            s  += vs[q];
            ne += vn[q];
            nv += vv[q];
        }
        for (int off = 32; off > 0; off >>= 1) {
            s  += __shfl_down(s,  off, 64);
            ne += __shfl_down(ne, off, 64);
            nv += __shfl_down(nv, off, 64);
        }
        __shared__ float fr_s[4];
        __shared__ unsigned long long fr_ne[4], fr_nv[4];
        if (lane == 0) { fr_s[wv] = s; fr_ne[wv] = ne; fr_nv[wv] = nv; }
        __syncthreads();
        if (tid == 0) {
            float ts = 0.f; unsigned long long tne = 0, tnv = 0;
            for (int w = 0; w < 4; ++w) { ts += fr_s[w]; tne += fr_ne[w]; tnv += fr_nv[w]; }
            float fne = (float)tne;
            float fnv = (float)tnv;
            out[0] = (fne > 0.f) ? (ts / fmaxf(fne, 1.f)) : 0.f;
            out[1] = fnv;
            out[2] = fne;
            out[3] = fne / (fnv + 1e-16f);
        }
    }
}

extern "C" void kernel_launch(void* const* d_in, const int* in_sizes, int n_in,
                              void* d_out, int out_size, void* d_ws, size_t ws_size,
                              hipStream_t stream) {
    const float* e  = (const float*)d_in[0];
    const int* lab  = (const int*)d_in[1];
    int n = in_sizes[1];           // 640
    int d = in_sizes[0] / n;       // 128

    // ws layout: partials (3 arrays of n) | counter | dist (n*n), 256B aligned
    char* ws = (char*)d_ws;
    float*        part_sum   = (float*)ws;
    unsigned int* part_ne    = (unsigned int*)(ws + (size_t)n * 4);
    unsigned int* part_valid = (unsigned int*)(ws + (size_t)n * 8);
    unsigned int* done_cnt   = (unsigned int*)(ws + (size_t)n * 12);
    size_t dist_off = ((size_t)n * 12 + 4 + 255) & ~(size_t)255;
    float*        dist       = (float*)(ws + dist_off);
    float*        outp       = (float*)d_out;

    int nt = (n + TILE - 1) / TILE;       // 20
    int nblk = n > nt * nt ? n : nt * nt; // 640

    void* args[] = { (void*)&e, (void*)&lab, (void*)&n, (void*)&d, (void*)&dist,
                     (void*)&part_sum, (void*)&part_ne, (void*)&part_valid,
                     (void*)&done_cnt, (void*)&outp };
    hipError_t err = hipLaunchCooperativeKernel((const void*)fused_all,
                                                dim3(nblk), dim3(256),
                                                args, 0, stream);
    if (err != hipSuccess) {
        // fallback: proven round-3 two-dispatch path
        dim3 grid(nt, nt);
        dist_kernel<<<grid, 256, 0, stream>>>(e, n, d, dist, done_cnt);
        triplet_kernel<<<n, 256, 0, stream>>>(dist, lab, n,
                                              part_sum, part_ne, part_valid,
                                              done_cnt, outp);
    }
}

// Round 5
// 73.684 us; speedup vs baseline: 2.1757x; 2.1757x over previous
//
#include <hip/hip_runtime.h>
#include <math.h>

#define MARGIN 1.9f
#define TILE 32
#define NMAX 1024   // max n supported by K2's LDS layout (n=640 here)

// ---------------------------------------------------------------------------
// K1: pairwise distance matrix via LDS-tiled "GEMM" on sum((a-b)^2).
// Grid (n/32, n/32), block 256 = 16x16 threads, each computes 2x2 outputs.
// Byte-for-byte the round-0 kernel (measured best, absmax 0.0).
// ---------------------------------------------------------------------------
__global__ __launch_bounds__(256) void dist_kernel(
        const float* __restrict__ e, int n, int d,
        float* __restrict__ dist)
{
    __shared__ float As[TILE * 132];
    __shared__ float Bs[TILE * 132];
    const int tid  = threadIdx.x;
    const int row0 = blockIdx.y * TILE;
    const int col0 = blockIdx.x * TILE;
    const int nf4  = d >> 2;                    // float4s per row (32)

    const float4* eg  = (const float4*)e;
    float4* As4 = (float4*)As;
    float4* Bs4 = (float4*)Bs;
    for (int f = tid; f < TILE * nf4; f += 256) {
        int r = f / nf4, c = f - r * nf4;
        int ga = row0 + r; if (ga >= n) ga = n - 1;   // clamp (n%32==0 here)
        int gb = col0 + r; if (gb >= n) gb = n - 1;
        As4[r * 33 + c] = eg[(size_t)ga * nf4 + c];
        Bs4[r * 33 + c] = eg[(size_t)gb * nf4 + c];
    }
    __syncthreads();

    const int tx = tid & 15, ty = tid >> 4;
    float a00 = 0.f, a01 = 0.f, a10 = 0.f, a11 = 0.f;
    for (int t = 0; t < nf4; ++t) {
        float4 A0 = As4[ty * 33 + t];
        float4 A1 = As4[(ty + 16) * 33 + t];
        float4 B0 = Bs4[tx * 33 + t];
        float4 B1 = Bs4[(tx + 16) * 33 + t];
        float dx;
#define ACC(acc, A, B, comp) dx = A.comp - B.comp; acc = fmaf(dx, dx, acc)
        ACC(a00, A0, B0, x); ACC(a00, A0, B0, y); ACC(a00, A0, B0, z); ACC(a00, A0, B0, w);
        ACC(a01, A0, B1, x); ACC(a01, A0, B1, y); ACC(a01, A0, B1, z); ACC(a01, A0, B1, w);
        ACC(a10, A1, B0, x); ACC(a10, A1, B0, y); ACC(a10, A1, B0, z); ACC(a10, A1, B0, w);
        ACC(a11, A1, B1, x); ACC(a11, A1, B1, y); ACC(a11, A1, B1, z); ACC(a11, A1, B1, w);
#undef ACC
    }

    const int r0 = row0 + ty, r1 = row0 + ty + 16;
    const int c0 = col0 + tx, c1 = col0 + tx + 16;
#define EMIT(rr, cc, acc) if ((rr) < n && (cc) < n) \
        dist[(size_t)(rr) * n + (cc)] = ((acc) == 0.f) ? 0.f : sqrtf(acc)
    EMIT(r0, c0, a00); EMIT(r0, c1, a01);
    EMIT(r1, c0, a10); EMIT(r1, c1, a11);
#undef EMIT
}

// ---------------------------------------------------------------------------
// K2: per-anchor triplet sweep. One block per anchor i. Round-0 body with a
// single change: the dist-row / labels staging loads are vectorized
// (float4 / int4) — identical LDS contents and ordering, 4x fewer load
// instructions. No atomics to global, no fences: visibility to K3 comes
// from the inter-dispatch barrier (r3 showed ticket+fence is a net loss).
// ---------------------------------------------------------------------------
__global__ __launch_bounds__(256) void triplet_kernel(
        const float* __restrict__ dist, const int* __restrict__ lab, int n,
        float* __restrict__ part_sum,          // [gridDim]
        unsigned int* __restrict__ part_ne,    // [gridDim]
        unsigned int* __restrict__ part_valid) // [gridDim]
{
    __shared__ float row[NMAX];
    __shared__ float pos[NMAX];
    __shared__ int   labs[NMAX];
    __shared__ int p_cnt, n_cnt;
    __shared__ float red_s[4];
    __shared__ unsigned int red_c[4];

    const int i    = blockIdx.x;
    const int tid  = threadIdx.x;
    const int lane = tid & 63;
    const int wv   = tid >> 6;

    if (tid == 0) { p_cnt = 0; n_cnt = 0; }

    // vectorized staging: n=640 -> 160 float4/int4 (n%4==0; rows 16B-aligned)
    {
        const int n4 = n >> 2;
        const float4* dr4 = (const float4*)(dist + (size_t)i * n);
        const int4*   lb4 = (const int4*)lab;
        float4* row4 = (float4*)row;
        int4*   lb_s = (int4*)labs;
        for (int j = tid; j < n4; j += 256) {
            row4[j] = dr4[j];
            lb_s[j] = lb4[j];
        }
        for (int j = (n & ~3) + tid; j < n; j += 256) {  // tail (unused, n%4==0)
            row[j]  = dist[(size_t)i * n + j];
            labs[j] = lab[j];
        }
    }
    __syncthreads();

    const int my_lab = labs[i];
    int local_neg = 0;
    for (int j = tid; j < n; j += 256) {
        if (labs[j] == my_lab) {
            if (j != i) { int k = atomicAdd(&p_cnt, 1); pos[k] = row[j]; }
        } else {
            local_neg++;
        }
    }
    for (int off = 32; off > 0; off >>= 1) local_neg += __shfl_down(local_neg, off, 64);
    if (lane == 0) atomicAdd(&n_cnt, local_neg);

    // negatives as INF-padded registers (NMAX/256 = 4 slots)
    const float INF = __builtin_huge_valf();
    int j0 = tid, j1 = tid + 256, j2 = tid + 512, j3 = tid + 768;
    float n0 = (j0 < n && labs[j0] != my_lab) ? row[j0] : INF;
    float n1 = (j1 < n && labs[j1] != my_lab) ? row[j1] : INF;
    float n2 = (j2 < n && labs[j2] != my_lab) ? row[j2] : INF;
    float n3 = (j3 < n && labs[j3] != my_lab) ? row[j3] : INF;
    __syncthreads();
    const int P = p_cnt, N = n_cnt;

    float sum = 0.f;
    unsigned int c = 0;
    for (int j = 0; j < P; ++j) {
        float a = pos[j] + MARGIN;        // LDS broadcast
        float t0 = a - n0; if (t0 > 0.f) { sum += t0; c++; }
        float t1 = a - n1; if (t1 > 0.f) { sum += t1; c++; }
        float t2 = a - n2; if (t2 > 0.f) { sum += t2; c++; }
        float t3 = a - n3; if (t3 > 0.f) { sum += t3; c++; }
    }

    for (int off = 32; off > 0; off >>= 1) {
        sum += __shfl_down(sum, off, 64);
        c   += __shfl_down(c,   off, 64);
    }
    if (lane == 0) { red_s[wv] = sum; red_c[wv] = c; }
    __syncthreads();

    if (tid == 0) {
        float s = 0.f; unsigned int cc = 0;
        for (int w = 0; w < 4; ++w) { s += red_s[w]; cc += red_c[w]; }
        part_sum[i]   = s;
        part_ne[i]    = cc;
        part_valid[i] = (unsigned int)P * (unsigned int)N;
    }
}

// ---------------------------------------------------------------------------
// K3: reduce 640 partials -> out[4] = {loss, num_valid, num_non_easy, frac}
// Byte-for-byte the round-0 kernel.
// ---------------------------------------------------------------------------
__global__ __launch_bounds__(256) void finalize_kernel(
        const float* __restrict__ part_sum,
        const unsigned int* __restrict__ part_ne,
        const unsigned int* __restrict__ part_valid,
        int nblk, float* __restrict__ out)
{
    __shared__ float red_s[4];
    __shared__ unsigned long long red_ne[4], red_nv[4];
    int tid = threadIdx.x;

    float s = 0.f;
    unsigned long long ne = 0, nv = 0;
    for (int b = tid; b < nblk; b += blockDim.x) {
        s  += part_sum[b];
        ne += part_ne[b];
        nv += part_valid[b];
    }
    for (int off = 32; off > 0; off >>= 1) {
        s  += __shfl_down(s,  off, 64);
        ne += __shfl_down(ne, off, 64);
        nv += __shfl_down(nv, off, 64);
    }
    int wave = tid >> 6;
    if ((tid & 63) == 0) { red_s[wave] = s; red_ne[wave] = ne; red_nv[wave] = nv; }
    __syncthreads();
    if (tid == 0) {
        float ts = 0.f; unsigned long long tne = 0, tnv = 0;
        int nwaves = (blockDim.x + 63) >> 6;
        for (int w = 0; w < nwaves; ++w) { ts += red_s[w]; tne += red_ne[w]; tnv += red_nv[w]; }
        float fne = (float)tne;
        float fnv = (float)tnv;
        out[0] = (fne > 0.f) ? (ts / fmaxf(fne, 1.f)) : 0.f;
        out[1] = fnv;
        out[2] = fne;
        out[3] = fne / (fnv + 1e-16f);
    }
}

extern "C" void kernel_launch(void* const* d_in, const int* in_sizes, int n_in,
                              void* d_out, int out_size, void* d_ws, size_t ws_size,
                              hipStream_t stream) {
    const float* e  = (const float*)d_in[0];
    const int* lab  = (const int*)d_in[1];
    int n = in_sizes[1];           // 640
    int d = in_sizes[0] / n;       // 128

    // ws layout: [0..] per-block partials (3 arrays of n) | then dist (n*n)
    char* ws = (char*)d_ws;
    float*        part_sum   = (float*)ws;
    unsigned int* part_ne    = (unsigned int*)(ws + (size_t)n * 4);
    unsigned int* part_valid = (unsigned int*)(ws + (size_t)n * 8);
    size_t dist_off = ((size_t)n * 12 + 255) & ~(size_t)255;
    float*        dist       = (float*)(ws + dist_off);

    int nt = (n + TILE - 1) / TILE;   // 20
    dim3 grid(nt, nt);
    dist_kernel<<<grid, 256, 0, stream>>>(e, n, d, dist);
    triplet_kernel<<<n, 256, 0, stream>>>(dist, lab, n,
                                          part_sum, part_ne, part_valid);
    finalize_kernel<<<1, 256, 0, stream>>>(part_sum, part_ne, part_valid,
                                           n, (float*)d_out);
}